// Round 5
// baseline (109.909 us; speedup 1.0000x reference)
//
#include <hip/hip_runtime.h>
#include <math.h>

#define IMG   512
#define NIMG  24
#define XST   72     // X stride (halfs): rows 16B-aligned
#define TST   104    // T' stride (row length 96)
#define RST   56     // R stride (row length 48)
#define UST   88     // U' stride (row length 80)

// ---- LDS pool layout (units: halfs), 32x64 output tile (R3 base) ----
// A: reads X [9984,16896), writes sTL/sTH [0,9984)
// B: reads sT,              writes R0..R2 [9984,23424)  (over dead X)
// C: reads R,               writes U0..U2 [0,8448)      (over dead sT)
// D: reads U.   ftab [22112,23424) read into regs pre-A; B overwrites after barrier.
#define SA_TL  0        // 48*104 = 4992
#define SA_TH  4992     // 4992
#define SA_X   9984     // 96*72 = 6912 (dead after A)
#define SA_R   9984     // 3 x 80*56 = 13440 -> [9984, 23424)
#define RSZ    4480
#define SA_U   0        // 3 x 32*88 -> [0, 8448)
#define USZ    2816
#define SA_FT  22112    // 4 modes x 41 starts x 8 = 1312 -> [22112, 23424)
#define POOLSZ 23424    // 46848 B -> 3 blocks/CU

typedef _Float16 v8h __attribute__((ext_vector_type(8)));
typedef float    v4f __attribute__((ext_vector_type(4)));

__device__ __forceinline__ v8h load8(const _Float16* p) {
    union { uint4 u; v8h h; } c;
    c.u = *(const uint4*)p;
    return c.h;
}

__device__ __forceinline__ unsigned pkrtz(float a, float b) {
    union { __fp16 __attribute__((ext_vector_type(2))) v; unsigned u; } c;
    c.v = __builtin_amdgcn_cvt_pkrtz(a, b);
    return c.u;
}

__device__ __forceinline__ void store4(_Float16* p, v4f a) {
    union { _Float16 h[4]; uint2 u; } c;
    c.h[0] = (_Float16)a[0]; c.h[1] = (_Float16)a[1];
    c.h[2] = (_Float16)a[2]; c.h[3] = (_Float16)a[3];
    *(uint2*)p = c.u;
}

__device__ __forceinline__ void store4abs(_Float16* p, v4f a) {
    union { _Float16 h[4]; uint2 u; } c;
    c.h[0] = (_Float16)fabsf(a[0]); c.h[1] = (_Float16)fabsf(a[1]);
    c.h[2] = (_Float16)fabsf(a[2]); c.h[3] = (_Float16)fabsf(a[3]);
    *(uint2*)p = c.u;
}

// float -> bf16 bits, round-to-nearest-even (input non-NaN)
__device__ __forceinline__ unsigned short f2bf(float f) {
    unsigned b = __float_as_uint(f);
    b = (b + 0x7fffu + ((b >> 16) & 1u)) >> 16;
    return (unsigned short)b;
}

__device__ __forceinline__ int refl(int g) {
    return g < 0 ? -g : (g >= IMG ? 2 * IMG - 2 - g : g);
}

// ---------------- stage 1: MFMA banded-conv pipeline, batched-issue phases ----------------
// modes: 0: h[v]  1: lpdf[v]=(-1)^v h[15-v]  2: |h[v]|  3: |h[15-v]|
__global__ __launch_bounds__(512, 6) void stego_stage1(
    const float* __restrict__ x, const float* __restrict__ hpdf,
    unsigned short* __restrict__ rho_out, float2* __restrict__ bmm)
{
    __shared__ __align__(16) _Float16 pool[POOLSZ];
    __shared__ float red[16];

    const int tid = threadIdx.x;
    const int lane = tid & 63;
    const int wid = __builtin_amdgcn_readfirstlane(tid >> 6);   // wave-uniform -> SALU
    const int n16 = lane & 15, quad = lane >> 4;

    // XCD-swizzled block decode: all 128 tiles of an image land on one XCD's L2
    const int blk = blockIdx.x;
    const int xcd = blk & 7;
    const int grp = blk >> 3;                 // 0..383
    const int img = xcd + ((grp >> 7) << 3);  // XCD c serves images {c, c+8, c+16}
    const int tl  = grp & 127;
    const int Oi = (tl >> 4) << 6;
    const int Oj = (tl & 15) << 5;
    const float* ximg = x + (size_t)img * (IMG * IMG);

    // ---- fragment-window table: ftab[(mode*41 + s)*8 + j] = c_mode[s + j - 16] ----
    for (int e = tid; e < 1312; e += 512) {
        const int mode = e / 328;
        const int rem  = e - mode * 328;
        const int tap  = (rem >> 3) + (rem & 7) - 16;      // s + j - 16
        float v = 0.f;
        if (tap >= 0 && tap <= 15) {
            int idx = (mode == 0 || mode == 2) ? tap : 15 - tap;
            float c = hpdf[idx];
            if (mode == 1 && (tap & 1)) c = -c;
            if (mode >= 2) c = fabsf(c);
            v = c;
        }
        pool[SA_FT + e] = (_Float16)v;
    }

    // ---- load X as fp16: rows Oi-15..Oi+78 (94 rows), cols Oj-16..Oj+47 (64 cols),
    //      rows 94..95 zeroed. Interior path: 3 aligned float4 loads / thread. ----
    {
        const int cg = tid & 15, row0 = tid >> 4;    // 16 col-quads x 32 rows, 3 steps
        const int c0 = Oj - 16 + 4 * cg;
        _Float16* dst = pool + SA_X + row0 * XST + 4 * cg;
        if (Oi >= 15 && Oi <= 433 && Oj >= 16 && Oj <= 464) {
            const float* src = ximg + (size_t)(Oi - 15 + row0) * IMG + c0;
            #pragma unroll
            for (int k = 0; k < 3; ++k) {
                const int row = row0 + (k << 5);
                uint2 pv = make_uint2(0u, 0u);
                if (row < 94) {
                    float4 xv = *(const float4*)(src + (size_t)(k << 5) * IMG);
                    pv.x = pkrtz(xv.x, xv.y);
                    pv.y = pkrtz(xv.z, xv.w);
                }
                *(uint2*)(dst + (size_t)(k << 5) * XST) = pv;
            }
        } else {
            const int gj0 = refl(c0),     gj1 = refl(c0 + 1);
            const int gj2 = refl(c0 + 2), gj3 = refl(c0 + 3);
            #pragma unroll
            for (int k = 0; k < 3; ++k) {
                const int row = row0 + (k << 5);
                uint2 pv = make_uint2(0u, 0u);
                if (row < 94) {
                    const float* rsrc = ximg + (size_t)refl(Oi - 15 + row) * IMG;
                    pv.x = pkrtz(rsrc[gj0], rsrc[gj1]);
                    pv.y = pkrtz(rsrc[gj2], rsrc[gj3]);
                }
                *(uint2*)(dst + (size_t)(k << 5) * XST) = pv;
            }
        }
    }
    __syncthreads();

    // ---- band fragments: one aligned ds_read_b128 per fragment.
    // band[4]: UNSHIFTED  B[k][n] = c[k-n]    (phases B, C, D)
    // bandA[2]: SHIFTED   B[k][n] = c[k-n-1]  (phase A only; X starts at Oj-16)
    v8h band[4], bandA[2];
    {
        const int sA = 16 + quad * 8 - n16;   // in [1,40]
        #pragma unroll
        for (int m = 0; m < 4; ++m)
            band[m] = load8(pool + SA_FT + (m * 41 + sA) * 8);
        #pragma unroll
        for (int m = 0; m < 2; ++m)
            bandA[m] = load8(pool + SA_FT + (m * 41 + sA - 1) * 8);
    }

    // ---- phase A: hconv X -> T_L', T_H' (18 tiles; batched loads) ----
    {
        const int laneX = n16 * XST + quad * 8;
        const int laneT = n16 * TST + quad * 4;
        const int u0 = wid, u1 = wid + 8, u2 = wid + 16;
        const int lo0 = (u0 % 6) * 16 * XST + (u0 / 6) * 16;
        const int lo1 = (u1 % 6) * 16 * XST + (u1 / 6) * 16;
        const int lo2 = (u2 % 6) * 16 * XST + (u2 / 6) * 16;
        const int so0 = (u0 / 6) * 16 * TST + (u0 % 6) * 16;
        const int so1 = (u1 / 6) * 16 * TST + (u1 % 6) * 16;
        const int so2 = (u2 / 6) * 16 * TST + (u2 % 6) * 16;
        v8h a0 = load8(pool + SA_X + lo0 + laneX);
        v8h a1 = load8(pool + SA_X + lo1 + laneX);
        v8h a2;
        if (wid < 2) a2 = load8(pool + SA_X + lo2 + laneX);
        const v4f z = {0.f, 0.f, 0.f, 0.f};
        v4f cL0 = __builtin_amdgcn_mfma_f32_16x16x32_f16(a0, bandA[1], z, 0, 0, 0);
        v4f cH0 = __builtin_amdgcn_mfma_f32_16x16x32_f16(a0, bandA[0], z, 0, 0, 0);
        v4f cL1 = __builtin_amdgcn_mfma_f32_16x16x32_f16(a1, bandA[1], z, 0, 0, 0);
        v4f cH1 = __builtin_amdgcn_mfma_f32_16x16x32_f16(a1, bandA[0], z, 0, 0, 0);
        store4(pool + SA_TL + so0 + laneT, cL0);
        store4(pool + SA_TH + so0 + laneT, cH0);
        store4(pool + SA_TL + so1 + laneT, cL1);
        store4(pool + SA_TH + so1 + laneT, cH1);
        if (wid < 2) {
            v4f cL2 = __builtin_amdgcn_mfma_f32_16x16x32_f16(a2, bandA[1], z, 0, 0, 0);
            v4f cH2 = __builtin_amdgcn_mfma_f32_16x16x32_f16(a2, bandA[0], z, 0, 0, 0);
            store4(pool + SA_TL + so2 + laneT, cL2);
            store4(pool + SA_TH + so2 + laneT, cH2);
        }
    }
    __syncthreads();

    // ---- phase B: vconv T -> R_f = |.| (45 tasks flat; batched loads) ----
    // task v: f = v/15, nt = (v%15)%5, mt = (v%15)/5; i0=nt*16 (K row), c0=mt*16 (T col)
    {
        const int laneTB = n16 * TST + quad * 8;
        const int laneR  = n16 * RST + quad * 4;
        int ulo[6], uso[6], uf[6];
        #pragma unroll
        for (int k = 0; k < 6; ++k) {
            const int v = (k < 5) ? (wid + 8 * k) : (40 + wid);
            const int f = v / 15, rem = v - 15 * f;
            const int i0 = (rem % 5) * 16, c0 = (rem / 5) * 16;
            ulo[k] = (f == 0 ? SA_TL : SA_TH) + c0 * TST + i0;
            uso[k] = SA_R + f * RSZ + i0 * RST + c0;
            uf[k]  = f;
        }
        v8h aB[6];
        #pragma unroll
        for (int k = 0; k < 6; ++k)
            if (k < 5 || wid < 5) aB[k] = load8(pool + ulo[k] + laneTB);
        #pragma unroll
        for (int k = 0; k < 6; ++k)
            if (k < 5 || wid < 5) {
                const v4f z = {0.f, 0.f, 0.f, 0.f};
                v4f acc = __builtin_amdgcn_mfma_f32_16x16x32_f16(
                    aB[k], (uf[k] == 1) ? band[1] : band[0], z, 0, 0, 0);
                store4abs(pool + uso[k] + laneR, acc);
            }
    }
    __syncthreads();

    // ---- phase C: hconv R_f -> U'_f (30 tasks flat; batched loads) ----
    // task v: f = v/10, mt = (v%10)%5, nt = (v%10)/5; i0=mt*16 (R row), j0=nt*16 (out col)
    {
        const int laneRC = n16 * RST + quad * 8;
        const int laneU  = n16 * UST + quad * 4;
        int ulo[4], uso[4], uf[4];
        #pragma unroll
        for (int k = 0; k < 4; ++k) {
            const int v = (k < 3) ? (wid + 8 * k) : (24 + wid);
            const int f = v / 10, rem = v - 10 * f;
            const int i0 = (rem % 5) * 16, j0 = (rem / 5) * 16;
            ulo[k] = SA_R + f * RSZ + i0 * RST + j0;
            uso[k] = SA_U + f * USZ + j0 * UST + i0;
            uf[k]  = f;
        }
        v8h aC[4];
        #pragma unroll
        for (int k = 0; k < 4; ++k)
            if (k < 3 || wid < 6) aC[k] = load8(pool + ulo[k] + laneRC);
        #pragma unroll
        for (int k = 0; k < 4; ++k)
            if (k < 3 || wid < 6) {
                const v4f z = {0.f, 0.f, 0.f, 0.f};
                v4f acc = __builtin_amdgcn_mfma_f32_16x16x32_f16(
                    aC[k], (uf[k] == 0) ? band[2] : band[3], z, 0, 0, 0);
                store4(pool + uso[k] + laneU, acc);
            }
    }
    __syncthreads();

    // ---- phase D: vconv U_f -> xi; rho += 1/xi (24 tiles; batched loads) ----
    float rho[4];
    {
        const int i0 = (wid & 3) * 16, c0 = (wid >> 2) * 16;
        const int laneUD = n16 * UST + quad * 8;
        const int ub = c0 * UST + i0 + laneUD;
        v8h d0 = load8(pool + SA_U + 0 * USZ + ub);
        v8h d1 = load8(pool + SA_U + 1 * USZ + ub);
        v8h d2 = load8(pool + SA_U + 2 * USZ + ub);
        const v4f z = {0.f, 0.f, 0.f, 0.f};
        v4f x0 = __builtin_amdgcn_mfma_f32_16x16x32_f16(d0, band[3], z, 0, 0, 0);  // fD[0]=3
        v4f x1 = __builtin_amdgcn_mfma_f32_16x16x32_f16(d1, band[2], z, 0, 0, 0);  // fD[1]=2
        v4f x2 = __builtin_amdgcn_mfma_f32_16x16x32_f16(d2, band[3], z, 0, 0, 0);  // fD[2]=3
        #pragma unroll
        for (int r = 0; r < 4; ++r)
            rho[r] = __builtin_amdgcn_rcpf(x0[r]) + __builtin_amdgcn_rcpf(x1[r])
                   + __builtin_amdgcn_rcpf(x2[r]);
    }

    // ---- finalize: clamp/NaN, bf16 round, NATURAL-layout aligned uint2 store;
    //      roll applied at stage2 read. Per-block min/max unchanged. ----
    const size_t rbase = (size_t)img * (IMG * IMG);
    const int i_nat = Oi + (wid & 3) * 16 + n16;
    const int jb = Oj + ((wid >> 2) << 4) + quad * 4;
    float lmin = 1e38f, lmax = 0.f;
    unsigned pk0, pk1;
    {
        unsigned short b[4];
        #pragma unroll
        for (int r = 0; r < 4; ++r) {
            float v = rho[r];
            v = isnan(v) ? 1e10f : fminf(v, 1e10f);
            b[r] = f2bf(v);
            float rq = __uint_as_float((unsigned)b[r] << 16);
            lmin = fminf(lmin, rq);
            lmax = fmaxf(lmax, rq);
        }
        pk0 = (unsigned)b[0] | ((unsigned)b[1] << 16);
        pk1 = (unsigned)b[2] | ((unsigned)b[3] << 16);
    }
    *(uint2*)(rho_out + rbase + ((size_t)i_nat << 9) + jb) = make_uint2(pk0, pk1);

    #pragma unroll
    for (int off = 32; off >= 1; off >>= 1) {
        lmin = fminf(lmin, __shfl_xor(lmin, off));
        lmax = fmaxf(lmax, __shfl_xor(lmax, off));
    }
    if ((tid & 63) == 0) { red[wid] = lmin; red[8 + wid] = lmax; }
    __syncthreads();
    if (tid == 0) {
        float m0 = red[0], m1 = red[8];
        #pragma unroll
        for (int k = 1; k < 8; ++k) { m0 = fminf(m0, red[k]); m1 = fmaxf(m1, red[8 + k]); }
        bmm[(img << 7) + tl] = make_float2(m0, m1);
    }
}

// ---------------- stage 2: reduce minmax + rolled read + normalize + sigmoid + multiply ----------------
__global__ __launch_bounds__(256) void stego_stage2(
    const float* __restrict__ x, const unsigned short* __restrict__ rho,
    const float2* __restrict__ bmm, float* __restrict__ out)
{
    __shared__ float sred[8];
    const int tid = threadIdx.x;
    const int lane = tid & 63;

    // same XCD swizzle as stage1: read rho/x from the L2 that produced them
    const int blk = blockIdx.x;
    const int xcd = blk & 7, grp = blk >> 3;
    const int img = xcd + ((grp >> 7) << 3);
    const int chunk = grp & 127;                 // 128 blocks per image, 4 rows each
    const int t = (img << 15) + (chunk << 8) + tid;

    float lmn = 1e38f, lmx = 0.f;
    if (tid < 128) { float2 p = bmm[(img << 7) + tid]; lmn = p.x; lmx = p.y; }
    #pragma unroll
    for (int off = 32; off >= 1; off >>= 1) {
        lmn = fminf(lmn, __shfl_xor(lmn, off));
        lmx = fmaxf(lmx, __shfl_xor(lmx, off));
    }
    if (tid < 128 && (tid & 63) == 0) { sred[tid >> 6] = lmn; sred[4 + (tid >> 6)] = lmx; }
    __syncthreads();
    const float mn = fminf(sred[0], sred[1]);
    const float mx = fmaxf(sred[4], sred[5]);
    const float inv = __builtin_amdgcn_rcpf(mx - mn + 1e-8f);

    // rolled rho: rho_rolled[i][j] = rho_nat[(i-1)&511][(j-1)&511].
    // One wave == one 512-px row, so the j-1 shift is a single intra-wave shfl.
    const int i = (t >> 6) & 511;
    const int rrow = (i - 1) & 511;
    const size_t rb_off = ((size_t)img << 18) + ((size_t)rrow << 9) + ((size_t)lane << 3);
    uint4 rb = *(const uint4*)(rho + rb_off);
    unsigned ru[4] = {rb.x, rb.y, rb.z, rb.w};
    float f7 = __uint_as_float(ru[3] & 0xffff0000u);   // nat col 8*lane+7
    float r[8];
    r[0] = __shfl(f7, (lane + 63) & 63);               // prev lane's col 7 (wraps to col 511)
    r[1] = __uint_as_float(ru[0] << 16);
    r[2] = __uint_as_float(ru[0] & 0xffff0000u);
    r[3] = __uint_as_float(ru[1] << 16);
    r[4] = __uint_as_float(ru[1] & 0xffff0000u);
    r[5] = __uint_as_float(ru[2] << 16);
    r[6] = __uint_as_float(ru[2] & 0xffff0000u);
    r[7] = __uint_as_float(ru[3] << 16);

    const size_t base = (size_t)t << 3;
    const float* xrow = x + base;
    float4 xa = *(const float4*)xrow;
    float4 xb = *(const float4*)(xrow + 4);
    float xs[8] = {xa.x, xa.y, xa.z, xa.w, xb.x, xb.y, xb.z, xb.w};
    float os[8];
    #pragma unroll
    for (int k = 0; k < 8; ++k) {
        float rn = (r[k] - mn) * inv;
        os[k] = xs[k] * __builtin_amdgcn_rcpf(1.f + __expf(rn - 1.f));  // x * sigmoid(1-rn)
    }
    float* orow = out + base;
    *(float4*)orow       = make_float4(os[0], os[1], os[2], os[3]);
    *(float4*)(orow + 4) = make_float4(os[4], os[5], os[6], os[7]);
}

extern "C" void kernel_launch(void* const* d_in, const int* in_sizes, int n_in,
                              void* d_out, int out_size, void* d_ws, size_t ws_size,
                              hipStream_t stream) {
    const float* x    = (const float*)d_in[0];
    const float* hpdf = (const float*)d_in[1];
    float* out = (float*)d_out;

    unsigned short* rho = (unsigned short*)d_ws;                         // 24*512*512 bf16
    float2* bmm = (float2*)((char*)d_ws + (size_t)NIMG * IMG * IMG * 2); // 24*128 float2

    hipLaunchKernelGGL(stego_stage1, dim3(NIMG * 128), dim3(512), 0, stream,
                       x, hpdf, rho, bmm);
    hipLaunchKernelGGL(stego_stage2, dim3(NIMG * 128), dim3(256), 0, stream,
                       x, rho, bmm, out);
}